// Round 15
// baseline (53.405 us; speedup 1.0000x reference)
//
#include <hip/hip_runtime.h>
#include <hip/hip_fp16.h>

// Coulomb pair-energy reduction: 2D pair bucketing, atomic-free block-major
// binning + LDS-staged quantized atom tiles (8B: u16 frac coords + f16 charge).
// R14: R13 base (best measured, 49.4us) + ONE change: finalize fused into
// bucket_compute via last-arriving-block reduce (ctr zeroed by scatter blk 0).

constexpr int TPB = 256;

constexpr int CHUNK_SHIFT = 13;
constexpr int CHUNK       = 1 << CHUNK_SHIFT;   // 8192 atoms/chunk
constexpr int NCHUNK_MAX  = 15;
constexpr int NB_MAX      = 256;

constexpr int S_TPB = 512;
constexpr int S_PPT = 16;                       // pairs per thread
constexpr int S_PPB = S_TPB * S_PPT;            // 8192 pairs/block
constexpr int S_I4  = S_PPB / 2;                // 4096 int4 per block
constexpr int S_UI  = S_I4 / S_TPB;             // 8 int4 per thread

constexpr int C_TPB   = 1024;
constexpr int C_SPLIT = 3;
constexpr int C_NW    = C_TPB / 64;

// ws layout (bytes)
constexpr size_t WS_ACC   = 0;      // double (fallback path only)
constexpr size_t WS_PAR   = 16;     // float[24] (fallback path only)
constexpr size_t WS_CTR   = 2048;   // u32 done-counter (zeroed by scatter blk 0)
constexpr size_t WS_PARTS = 4096;   // double[<=4096] per-block partials
constexpr size_t WS_TABLE = 36864;

// par: [0..8] boxInv, [9] cutoff^2, [10] shift, [11..19] box/65536, [20] diag
__device__ __forceinline__ void compute_par(const float* __restrict__ box,
                                            const float* __restrict__ cutoff_p,
                                            const int* __restrict__ do_shift_p,
                                            float* par) {
    float b00 = box[0], b01 = box[1], b02 = box[2];
    float b10 = box[3], b11 = box[4], b12 = box[5];
    float b20 = box[6], b21 = box[7], b22 = box[8];
    float det = b00*(b11*b22 - b12*b21)
              - b01*(b10*b22 - b12*b20)
              + b02*(b10*b21 - b11*b20);
    float id = 1.0f / det;
    par[0] =  (b11*b22 - b12*b21) * id;
    par[1] = -(b01*b22 - b02*b21) * id;
    par[2] =  (b01*b12 - b02*b11) * id;
    par[3] = -(b10*b22 - b12*b20) * id;
    par[4] =  (b00*b22 - b02*b20) * id;
    par[5] = -(b00*b12 - b02*b10) * id;
    par[6] =  (b10*b21 - b11*b20) * id;
    par[7] = -(b00*b21 - b01*b20) * id;
    par[8] =  (b00*b11 - b01*b10) * id;
    float cut = *cutoff_p;
    par[9]  = cut * cut;
    par[10] = (*do_shift_p) ? (1.0f / cut) : 0.0f;
    constexpr float S = 1.0f / 65536.0f;
    par[11] = b00*S; par[12] = b01*S; par[13] = b02*S;
    par[14] = b10*S; par[15] = b11*S; par[16] = b12*S;
    par[17] = b20*S; par[18] = b21*S; par[19] = b22*S;
    float offd = fabsf(b01) + fabsf(b02) + fabsf(b10)
               + fabsf(b12) + fabsf(b20) + fabsf(b21);
    par[20] = (offd == 0.0f) ? 1.0f : 0.0f;
}

// ---------------- scatter (+ fused atom pack) ------------------------------

__global__ __launch_bounds__(S_TPB)
void scatter_kernel(const int4* __restrict__ pairs4, int npair2, int nchunk,
                    int nbucket, int nsb,
                    const float* __restrict__ coords,
                    const float* __restrict__ charges,
                    const float* __restrict__ box,
                    const float* __restrict__ cutoff_p,
                    const int* __restrict__ do_shift_p,
                    uint2* __restrict__ qatoms, int natoms,
                    unsigned* __restrict__ ctr,
                    unsigned* __restrict__ tableT,   // [nbucket+1][nsb]
                    unsigned* __restrict__ bdata) {
    __shared__ __align__(16) unsigned ordered[S_PPB];   // 32KB
    __shared__ unsigned hist[NB_MAX];
    __shared__ unsigned sA[NB_MAX], sB[NB_MAX];

    int tid = threadIdx.x;
    int blk = blockIdx.x;

    if (blk == 0 && tid == 0) *ctr = 0u;   // compute runs after scatter drains

    // fused atom pack: this block's slice
    {
        float par[21];
        compute_par(box, cutoff_p, do_shift_p, par);
        int per = (natoms + nsb - 1) / nsb;
        int a0 = blk * per;
        int a1 = min(natoms, a0 + per);
        for (int i = a0 + tid; i < a1; i += S_TPB) {
            float x = coords[3*i], y = coords[3*i+1], z = coords[3*i+2];
            float sx = x*par[0] + y*par[3] + z*par[6];
            float sy = x*par[1] + y*par[4] + z*par[7];
            float sz = x*par[2] + y*par[5] + z*par[8];
            unsigned qx = (unsigned)__float2int_rn(sx * 65536.0f) & 0xFFFFu;
            unsigned qy = (unsigned)__float2int_rn(sy * 65536.0f) & 0xFFFFu;
            unsigned qz = (unsigned)__float2int_rn(sz * 65536.0f) & 0xFFFFu;
            unsigned qc = (unsigned)__half_as_ushort(__float2half(charges[i]));
            qatoms[i] = make_uint2(qx | (qy << 16), qz | (qc << 16));
        }
    }

    for (int t = tid; t < NB_MAX; t += S_TPB) hist[t] = 0u;
    __syncthreads();

    int base4 = blk * S_I4;
    unsigned k[S_PPT];
    unsigned bs[S_PPT];   // bucket (8b) | seq<<8 ; 0xFFFFFFFF = invalid
#pragma unroll
    for (int u = 0; u < S_UI; ++u) {
        int i4 = base4 + u * S_TPB + tid;
        bool v = (i4 < npair2);
        int4 pp = v ? pairs4[i4] : make_int4(0, 0, 0, 0);
        int u2 = 2 * u;
        if (v) {
            int b0 = (pp.x >> CHUNK_SHIFT) * nchunk + (pp.y >> CHUNK_SHIFT);
            int b1 = (pp.z >> CHUNK_SHIFT) * nchunk + (pp.w >> CHUNK_SHIFT);
            k[u2]     = ((unsigned)(pp.x & (CHUNK-1)) << 16) | (unsigned)(pp.y & (CHUNK-1));
            k[u2 + 1] = ((unsigned)(pp.z & (CHUNK-1)) << 16) | (unsigned)(pp.w & (CHUNK-1));
            unsigned s0 = atomicAdd(&hist[b0], 1u);   // seq = pre-count
            bs[u2] = (unsigned)b0 | (s0 << 8);
            unsigned s1 = atomicAdd(&hist[b1], 1u);
            bs[u2 + 1] = (unsigned)b1 | (s1 << 8);
        } else {
            bs[u2] = 0xFFFFFFFFu; bs[u2 + 1] = 0xFFFFFFFFu;
        }
    }
    __syncthreads();

    // exclusive scan over NB_MAX (Hillis-Steele, ping-pong)
    unsigned *pa = sA, *pb = sB;
    if (tid < NB_MAX) pa[tid] = hist[tid];
    __syncthreads();
    for (int d = 1; d < NB_MAX; d <<= 1) {
        if (tid < NB_MAX) {
            unsigned v = pa[tid];
            if (tid >= d) v += pa[tid - d];
            pb[tid] = v;
        }
        __syncthreads();
        unsigned* t = pa; pa = pb; pb = t;
    }
    // pa = inclusive scan; write TRANSPOSED table column; stash excl in hist
    if (tid <= nbucket) {
        unsigned excl = (tid == 0) ? 0u : pa[tid - 1];
        tableT[(size_t)tid * nsb + blk] = excl;
        if (tid < nbucket) hist[tid] = excl;
    }
    __syncthreads();

    // LDS scatter: slot = excl[bucket] + seq  (no second atomic pass)
#pragma unroll
    for (int u = 0; u < S_PPT; ++u) {
        if (bs[u] != 0xFFFFFFFFu) {
            unsigned b = bs[u] & 0xFFu;
            unsigned slot = hist[b] + (bs[u] >> 8);
            ordered[slot] = k[u];
        }
    }
    __syncthreads();

    // coalesced burst writeout
    unsigned total = pa[nbucket - 1];
    unsigned* dst = bdata + (size_t)blk * S_PPB;
    unsigned n4 = total >> 2;
    const uint4* o4 = (const uint4*)ordered;
    for (unsigned i = tid; i < n4; i += S_TPB)
        ((uint4*)dst)[i] = o4[i];
    for (unsigned i = (n4 << 2) + tid; i < total; i += S_TPB)
        dst[i] = ordered[i];
}

// ---------------- per-bucket compute (+ fused last-block finalize) ---------

template<bool DIAG>
__device__ __forceinline__ float pair_ener(const uint2* tA, const uint2* tB,
                                           unsigned key, const float* P,
                                           bool valid) {
    uint2 ri = tA[key >> 16];
    uint2 rj = tB[key & 0xFFFFu];
    float dx = (float)(short)(ri.x - rj.x);
    float dy = (float)(short)((ri.x >> 16) - (rj.x >> 16));
    float dz = (float)(short)(ri.y - rj.y);
    float px, py, pz;
    if (DIAG) {
        px = dx * P[11]; py = dy * P[15]; pz = dz * P[19];
    } else {
        px = dx*P[11] + dy*P[14] + dz*P[17];
        py = dx*P[12] + dy*P[15] + dz*P[18];
        pz = dx*P[13] + dy*P[16] + dz*P[19];
    }
    float r2 = px*px + py*py + pz*pz;
    float rinv = rsqrtf(r2);
    float qi = __half2float(__ushort_as_half((unsigned short)(ri.y >> 16)));
    float qj = __half2float(__ushort_as_half((unsigned short)(rj.y >> 16)));
    float e = qi * qj * (rinv - P[10]);
    return (valid && r2 <= P[9]) ? e : 0.0f;
}

// software-pipelined walk (R11 verbatim)
template<bool DIAG>
__device__ double walk(const unsigned* __restrict__ bdata,
                       const unsigned* __restrict__ rowB,
                       const unsigned* __restrict__ rowB1,
                       int sA0, int cnt, int lane,
                       const uint2* tA, const uint2* tB, const float* P) {
    double lsum0 = 0.0, lsum1 = 0.0;
    for (int batch = 0; batch < cnt; batch += 64) {
        int bc = min(64, cnt - batch);
        unsigned o0v = 0u, lnv = 0u;
        if (lane < bc) {
            int s = sA0 + batch + lane;
            unsigned a0 = rowB[s];
            o0v = a0;
            lnv = rowB1[s] - a0;
        }
        unsigned cl0, cl1, cl2, cl3;
        size_t   cb0, cb1, cb2, cb3;
        unsigned ck0, ck1, ck2, ck3;
        {
            unsigned o0 = (unsigned)__shfl((int)o0v, 0);
            cl0 = (0 < bc) ? (unsigned)__shfl((int)lnv, 0) : 0u;
            cb0 = (size_t)(sA0 + batch + 0) * S_PPB + o0;
            unsigned o1 = (unsigned)__shfl((int)o0v, 1);
            cl1 = (1 < bc) ? (unsigned)__shfl((int)lnv, 1) : 0u;
            cb1 = (size_t)(sA0 + batch + 1) * S_PPB + o1;
            unsigned o2 = (unsigned)__shfl((int)o0v, 2);
            cl2 = (2 < bc) ? (unsigned)__shfl((int)lnv, 2) : 0u;
            cb2 = (size_t)(sA0 + batch + 2) * S_PPB + o2;
            unsigned o3 = (unsigned)__shfl((int)o0v, 3);
            cl3 = (3 < bc) ? (unsigned)__shfl((int)lnv, 3) : 0u;
            cb3 = (size_t)(sA0 + batch + 3) * S_PPB + o3;
            ck0 = (lane < (int)cl0) ? bdata[cb0 + lane] : 0u;
            ck1 = (lane < (int)cl1) ? bdata[cb1 + lane] : 0u;
            ck2 = (lane < (int)cl2) ? bdata[cb2 + lane] : 0u;
            ck3 = (lane < (int)cl3) ? bdata[cb3 + lane] : 0u;
        }
        for (int kk = 0; kk < bc; kk += 4) {
            unsigned nl0 = 0u, nl1 = 0u, nl2 = 0u, nl3 = 0u;
            size_t   nb0 = 0,  nb1 = 0,  nb2 = 0,  nb3 = 0;
            unsigned nk0 = 0u, nk1 = 0u, nk2 = 0u, nk3 = 0u;
            if (kk + 4 < bc) {
                unsigned o0 = (unsigned)__shfl((int)o0v, kk + 4);
                nl0 = (unsigned)__shfl((int)lnv, kk + 4);
                nb0 = (size_t)(sA0 + batch + kk + 4) * S_PPB + o0;
                unsigned o1 = (unsigned)__shfl((int)o0v, kk + 5);
                nl1 = (kk + 5 < bc) ? (unsigned)__shfl((int)lnv, kk + 5) : 0u;
                nb1 = (size_t)(sA0 + batch + kk + 5) * S_PPB + o1;
                unsigned o2 = (unsigned)__shfl((int)o0v, kk + 6);
                nl2 = (kk + 6 < bc) ? (unsigned)__shfl((int)lnv, kk + 6) : 0u;
                nb2 = (size_t)(sA0 + batch + kk + 6) * S_PPB + o2;
                unsigned o3 = (unsigned)__shfl((int)o0v, kk + 7);
                nl3 = (kk + 7 < bc) ? (unsigned)__shfl((int)lnv, kk + 7) : 0u;
                nb3 = (size_t)(sA0 + batch + kk + 7) * S_PPB + o3;
                nk0 = (lane < (int)nl0) ? bdata[nb0 + lane] : 0u;
                nk1 = (lane < (int)nl1) ? bdata[nb1 + lane] : 0u;
                nk2 = (lane < (int)nl2) ? bdata[nb2 + lane] : 0u;
                nk3 = (lane < (int)nl3) ? bdata[nb3 + lane] : 0u;
            }
            lsum0 += (double)pair_ener<DIAG>(tA, tB, ck0, P, lane < (int)cl0);
            lsum1 += (double)pair_ener<DIAG>(tA, tB, ck1, P, lane < (int)cl1);
            lsum0 += (double)pair_ener<DIAG>(tA, tB, ck2, P, lane < (int)cl2);
            lsum1 += (double)pair_ener<DIAG>(tA, tB, ck3, P, lane < (int)cl3);
            if (cl0 > 64u) for (unsigned e = 64u + lane; e < cl0; e += 64u)
                lsum0 += (double)pair_ener<DIAG>(tA, tB, bdata[cb0 + e], P, true);
            if (cl1 > 64u) for (unsigned e = 64u + lane; e < cl1; e += 64u)
                lsum1 += (double)pair_ener<DIAG>(tA, tB, bdata[cb1 + e], P, true);
            if (cl2 > 64u) for (unsigned e = 64u + lane; e < cl2; e += 64u)
                lsum0 += (double)pair_ener<DIAG>(tA, tB, bdata[cb2 + e], P, true);
            if (cl3 > 64u) for (unsigned e = 64u + lane; e < cl3; e += 64u)
                lsum1 += (double)pair_ener<DIAG>(tA, tB, bdata[cb3 + e], P, true);
            ck0 = nk0; ck1 = nk1; ck2 = nk2; ck3 = nk3;
            cl0 = nl0; cl1 = nl1; cl2 = nl2; cl3 = nl3;
            cb0 = nb0; cb1 = nb1; cb2 = nb2; cb3 = nb3;
        }
    }
    return lsum0 + lsum1;
}

__global__ __launch_bounds__(C_TPB)
void bucket_compute(const unsigned* __restrict__ bdata,
                    const unsigned* __restrict__ tableT, int nsb,
                    const uint2* __restrict__ qatoms, int natoms, int nchunk,
                    const float* __restrict__ box,
                    const float* __restrict__ cutoff_p,
                    const int* __restrict__ do_shift_p,
                    const float* __restrict__ prefac_p,
                    const float* __restrict__ coords,
                    const float* __restrict__ charges,
                    const int* __restrict__ pairs, int npairs,
                    double* __restrict__ parts, unsigned* __restrict__ ctr,
                    int cblocks, float* __restrict__ out) {
    __shared__ __align__(16) uint2 tA[CHUNK];
    __shared__ __align__(16) uint2 tB[CHUNK];
    __shared__ double wsum[C_NW];
    __shared__ float sP[21];
    __shared__ unsigned s_rank;

    if (threadIdx.x == 0) compute_par(box, cutoff_p, do_shift_p, sP);

    int b    = blockIdx.x / C_SPLIT;
    int part = blockIdx.x - b * C_SPLIT;
    int bx = b / nchunk, by = b - bx * nchunk;
    int gx = bx << CHUNK_SHIFT, gy = by << CHUNK_SHIFT;

    // uint4 tile staging: 2 atoms/load, chunk-level bounds check
    {
        const uint4* qa4 = reinterpret_cast<const uint4*>(qatoms);
        uint4* tA4 = reinterpret_cast<uint4*>(tA);
        uint4* tB4 = reinterpret_cast<uint4*>(tB);
        if (gx + CHUNK <= natoms) {
            int gx2 = gx >> 1;
            for (int t = threadIdx.x; t < CHUNK / 2; t += C_TPB)
                tA4[t] = qa4[gx2 + t];
        } else {
            for (int t = threadIdx.x; t < CHUNK; t += C_TPB) {
                int ga = gx + t;
                tA[t] = (ga < natoms) ? qatoms[ga] : make_uint2(0u, 0u);
            }
        }
        if (gy + CHUNK <= natoms) {
            int gy2 = gy >> 1;
            for (int t = threadIdx.x; t < CHUNK / 2; t += C_TPB)
                tB4[t] = qa4[gy2 + t];
        } else {
            for (int t = threadIdx.x; t < CHUNK; t += C_TPB) {
                int gb = gy + t;
                tB[t] = (gb < natoms) ? qatoms[gb] : make_uint2(0u, 0u);
            }
        }
    }
    __syncthreads();

    float P[21];
#pragma unroll
    for (int k = 0; k < 21; ++k) P[k] = sP[k];

    int s0 = (int)(((long long)part * nsb) / C_SPLIT);
    int s1 = (int)(((long long)(part + 1) * nsb) / C_SPLIT);
    int lane = threadIdx.x & 63;
    int wid  = threadIdx.x >> 6;

    int nseg = s1 - s0;
    int spw  = (nseg + C_NW - 1) / C_NW;
    int sA0  = s0 + wid * spw;
    int cnt  = min(spw, s1 - sA0);
    if (cnt < 0) cnt = 0;

    const unsigned* rowB  = tableT + (size_t)b * nsb;
    const unsigned* rowB1 = tableT + (size_t)(b + 1) * nsb;

    double lsum = (P[20] != 0.0f)
        ? walk<true >(bdata, rowB, rowB1, sA0, cnt, lane, tA, tB, P)
        : walk<false>(bdata, rowB, rowB1, sA0, cnt, lane, tA, tB, P);

#pragma unroll
    for (int off = 32; off > 0; off >>= 1)
        lsum += __shfl_down(lsum, off);

    if (lane == 0) wsum[wid] = lsum;
    __syncthreads();
    if (threadIdx.x == 0) {
        double s = 0.0;
#pragma unroll
        for (int w = 0; w < C_NW; ++w) s += wsum[w];
        parts[blockIdx.x] = s;
        __threadfence();
        s_rank = atomicAdd(ctr, 1u);
    }
    __syncthreads();

    // last-arriving block: deterministic fixed-order reduce + tail + output
    if (s_rank == (unsigned)(cblocks - 1)) {
        double s = 0.0;
        for (int i = threadIdx.x; i < cblocks; i += C_TPB) s += parts[i];
#pragma unroll
        for (int off = 32; off > 0; off >>= 1) s += __shfl_down(s, off);
        if (lane == 0) wsum[wid] = s;
        __syncthreads();
        if (threadIdx.x == 0) {
            double tot = 0.0;
#pragma unroll
            for (int w = 0; w < C_NW; ++w) tot += wsum[w];
            if (npairs & 1) {   // odd tail pair in f32
                int ii = pairs[2*(npairs-1)], jj = pairs[2*(npairs-1)+1];
                float dx = coords[3*ii]-coords[3*jj];
                float dy = coords[3*ii+1]-coords[3*jj+1];
                float dz = coords[3*ii+2]-coords[3*jj+2];
                float sx = dx*P[0]+dy*P[3]+dz*P[6];
                float sy = dx*P[1]+dy*P[4]+dz*P[7];
                float sz = dx*P[2]+dy*P[5]+dz*P[8];
                sx -= floorf(sx+0.5f); sy -= floorf(sy+0.5f); sz -= floorf(sz+0.5f);
                float px = (sx*P[11]+sy*P[14]+sz*P[17])*65536.0f;
                float py = (sx*P[12]+sy*P[15]+sz*P[18])*65536.0f;
                float pz = (sx*P[13]+sy*P[16]+sz*P[19])*65536.0f;
                float r2 = px*px+py*py+pz*pz;
                float e = charges[ii]*charges[jj]*(rsqrtf(r2)-P[10]);
                if (r2 <= P[9]) tot += (double)e;
            }
            out[0] = (float)(tot * (double)(*prefac_p));
        }
    }
}

// ---------------- fallback (direct gather, f32) ----------------

__global__ void setup_kernel(const float* __restrict__ box,
                             const float* __restrict__ cutoff_p,
                             const int* __restrict__ do_shift_p,
                             double* __restrict__ acc,
                             float* __restrict__ par) {
    if (threadIdx.x == 0 && blockIdx.x == 0) {
        *acc = 0.0;
        compute_par(box, cutoff_p, do_shift_p, par);
    }
}

__device__ __forceinline__ float pair_e_f(float4 ai, float4 aj, const float* P) {
    float dx = ai.x - aj.x, dy = ai.y - aj.y, dz = ai.z - aj.z;
    float sx = dx*P[0] + dy*P[3] + dz*P[6];
    float sy = dx*P[1] + dy*P[4] + dz*P[7];
    float sz = dx*P[2] + dy*P[5] + dz*P[8];
    sx -= floorf(sx + 0.5f);
    sy -= floorf(sy + 0.5f);
    sz -= floorf(sz + 0.5f);
    float px = (sx*P[11] + sy*P[14] + sz*P[17]) * 65536.0f;
    float py = (sx*P[12] + sy*P[15] + sz*P[18]) * 65536.0f;
    float pz = (sx*P[13] + sy*P[16] + sz*P[19]) * 65536.0f;
    float r2 = px*px + py*py + pz*pz;
    float rinv = rsqrtf(r2);
    float e = ai.w * aj.w * (rinv - P[10]);
    return (r2 <= P[9]) ? e : 0.0f;
}

__global__ __launch_bounds__(TPB)
void coulomb_direct(const int2* __restrict__ pairs, int npairs,
                    const float* __restrict__ coords,
                    const float* __restrict__ charges,
                    const float* __restrict__ par,
                    double* __restrict__ acc) {
    float P[21];
#pragma unroll
    for (int k = 0; k < 21; ++k) P[k] = par[k];
    double lsum = 0.0;
    int tid = blockIdx.x * blockDim.x + threadIdx.x;
    int stride = gridDim.x * blockDim.x;
    for (int p = tid; p < npairs; p += stride) {
        int2 pr = pairs[p];
        float4 a = make_float4(coords[3*pr.x], coords[3*pr.x+1], coords[3*pr.x+2], charges[pr.x]);
        float4 c = make_float4(coords[3*pr.y], coords[3*pr.y+1], coords[3*pr.y+2], charges[pr.y]);
        lsum += (double)pair_e_f(a, c, P);
    }
#pragma unroll
    for (int off = 32; off > 0; off >>= 1)
        lsum += __shfl_down(lsum, off);
    __shared__ double wsum[TPB / 64];
    int lane = threadIdx.x & 63;
    int wid  = threadIdx.x >> 6;
    if (lane == 0) wsum[wid] = lsum;
    __syncthreads();
    if (threadIdx.x == 0) {
        double s = 0.0;
#pragma unroll
        for (int w = 0; w < TPB / 64; ++w) s += wsum[w];
        atomicAdd(acc, s);
    }
}

__global__ void finalize_kernel(const double* __restrict__ acc,
                                const float* __restrict__ prefac_p,
                                float* __restrict__ out) {
    if (threadIdx.x == 0 && blockIdx.x == 0)
        out[0] = (float)(*acc * (double)(*prefac_p));
}

extern "C" void kernel_launch(void* const* d_in, const int* in_sizes, int n_in,
                              void* d_out, int out_size, void* d_ws, size_t ws_size,
                              hipStream_t stream) {
    const float* coords   = (const float*)d_in[0];
    const int*   pairs    = (const int*)d_in[1];
    const float* box      = (const float*)d_in[2];
    const float* charges  = (const float*)d_in[3];
    const float* prefac   = (const float*)d_in[4];
    const float* cutoff   = (const float*)d_in[5];
    const int*   do_shift = (const int*)d_in[6];
    float* out = (float*)d_out;

    int natoms = in_sizes[0] / 3;
    int npairs = in_sizes[1] / 2;
    int npair2 = npairs / 2;              // int4 count (even region)
    int npairs_even = npair2 * 2;

    int nchunk  = (natoms + CHUNK - 1) >> CHUNK_SHIFT;
    int nbucket = nchunk * nchunk;
    int nsb     = (npairs_even + S_PPB - 1) / S_PPB;

    size_t off_table  = WS_TABLE;
    size_t table_b    = (size_t)(nbucket + 1) * nsb * sizeof(unsigned);
    size_t off_qatoms = (off_table + table_b + 255) & ~(size_t)255;
    size_t off_bdata  = (off_qatoms + (size_t)natoms * sizeof(uint2) + 255) & ~(size_t)255;
    size_t need       = off_bdata + (size_t)nsb * S_PPB * sizeof(unsigned);

    int cblocks = nbucket * C_SPLIT;
    bool use_buckets = (nchunk <= NCHUNK_MAX) && (nbucket <= NB_MAX - 2) &&
                       (nsb >= 1) && (ws_size >= need) && (cblocks <= 4096);

    if (use_buckets) {
        unsigned* ctr    = (unsigned*)((char*)d_ws + WS_CTR);
        double*   parts  = (double*)((char*)d_ws + WS_PARTS);
        unsigned* tableT = (unsigned*)((char*)d_ws + off_table);
        uint2*    qatoms = (uint2*)((char*)d_ws + off_qatoms);
        unsigned* bdata  = (unsigned*)((char*)d_ws + off_bdata);

        scatter_kernel<<<nsb, S_TPB, 0, stream>>>(
            (const int4*)pairs, npair2, nchunk, nbucket, nsb,
            coords, charges, box, cutoff, do_shift, qatoms, natoms,
            ctr, tableT, bdata);

        bucket_compute<<<cblocks, C_TPB, 0, stream>>>(
            bdata, tableT, nsb, qatoms, natoms, nchunk,
            box, cutoff, do_shift, prefac, coords, charges, pairs, npairs,
            parts, ctr, cblocks, out);
    } else {
        double* acc = (double*)((char*)d_ws + WS_ACC);
        float*  par = (float*)((char*)d_ws + WS_PAR);
        setup_kernel<<<1, 64, 0, stream>>>(box, cutoff, do_shift, acc, par);
        int blocks = (npairs + TPB - 1) / TPB;
        if (blocks > 2048) blocks = 2048;
        coulomb_direct<<<blocks, TPB, 0, stream>>>(
            (const int2*)pairs, npairs, coords, charges, par, acc);
        finalize_kernel<<<1, 64, 0, stream>>>(acc, prefac, out);
    }
}

// Round 16
// 48.704 us; speedup vs baseline: 1.0965x; 1.0965x over previous
//
#include <hip/hip_runtime.h>
#include <hip/hip_fp16.h>

// Coulomb pair-energy reduction: 2D pair bucketing, atomic-free block-major
// binning + LDS-staged quantized atom tiles (8B: u16 frac coords + f16 charge).
// R15 = R13 verbatim (best measured: 49.4us). R14's fused finalize regressed
// (+4us: per-block threadfence + same-line atomic tail) and is reverted.
//   - scatter: fused atom pack, seq-from-histogram single-atomic-pass,
//     32KB LDS ordered buffer, coalesced burst writeout, transposed table
//   - compute: C_SPLIT=3 (507 blocks ~ 1.98 rounds), uint4 tile staging,
//     software-pipelined walk, DIAG fast path, per-block partials
//   - separate tiny finalize kernel (fixed-order deterministic sum)

constexpr int TPB = 256;

constexpr int CHUNK_SHIFT = 13;
constexpr int CHUNK       = 1 << CHUNK_SHIFT;   // 8192 atoms/chunk
constexpr int NCHUNK_MAX  = 15;
constexpr int NB_MAX      = 256;

constexpr int S_TPB = 512;
constexpr int S_PPT = 16;                       // pairs per thread
constexpr int S_PPB = S_TPB * S_PPT;            // 8192 pairs/block
constexpr int S_I4  = S_PPB / 2;                // 4096 int4 per block
constexpr int S_UI  = S_I4 / S_TPB;             // 8 int4 per thread

constexpr int C_TPB   = 1024;
constexpr int C_SPLIT = 3;
constexpr int C_NW    = C_TPB / 64;

// ws layout (bytes)
constexpr size_t WS_ACC   = 0;      // double (fallback path only)
constexpr size_t WS_PAR   = 16;     // float[24] (fallback path only)
constexpr size_t WS_PARTS = 4096;   // double[<=4096] per-block partials
constexpr size_t WS_TABLE = 36864;

// par: [0..8] boxInv, [9] cutoff^2, [10] shift, [11..19] box/65536, [20] diag
__device__ __forceinline__ void compute_par(const float* __restrict__ box,
                                            const float* __restrict__ cutoff_p,
                                            const int* __restrict__ do_shift_p,
                                            float* par) {
    float b00 = box[0], b01 = box[1], b02 = box[2];
    float b10 = box[3], b11 = box[4], b12 = box[5];
    float b20 = box[6], b21 = box[7], b22 = box[8];
    float det = b00*(b11*b22 - b12*b21)
              - b01*(b10*b22 - b12*b20)
              + b02*(b10*b21 - b11*b20);
    float id = 1.0f / det;
    par[0] =  (b11*b22 - b12*b21) * id;
    par[1] = -(b01*b22 - b02*b21) * id;
    par[2] =  (b01*b12 - b02*b11) * id;
    par[3] = -(b10*b22 - b12*b20) * id;
    par[4] =  (b00*b22 - b02*b20) * id;
    par[5] = -(b00*b12 - b02*b10) * id;
    par[6] =  (b10*b21 - b11*b20) * id;
    par[7] = -(b00*b21 - b01*b20) * id;
    par[8] =  (b00*b11 - b01*b10) * id;
    float cut = *cutoff_p;
    par[9]  = cut * cut;
    par[10] = (*do_shift_p) ? (1.0f / cut) : 0.0f;
    constexpr float S = 1.0f / 65536.0f;
    par[11] = b00*S; par[12] = b01*S; par[13] = b02*S;
    par[14] = b10*S; par[15] = b11*S; par[16] = b12*S;
    par[17] = b20*S; par[18] = b21*S; par[19] = b22*S;
    float offd = fabsf(b01) + fabsf(b02) + fabsf(b10)
               + fabsf(b12) + fabsf(b20) + fabsf(b21);
    par[20] = (offd == 0.0f) ? 1.0f : 0.0f;
}

// ---------------- scatter (+ fused atom pack) ------------------------------

__global__ __launch_bounds__(S_TPB)
void scatter_kernel(const int4* __restrict__ pairs4, int npair2, int nchunk,
                    int nbucket, int nsb,
                    const float* __restrict__ coords,
                    const float* __restrict__ charges,
                    const float* __restrict__ box,
                    const float* __restrict__ cutoff_p,
                    const int* __restrict__ do_shift_p,
                    uint2* __restrict__ qatoms, int natoms,
                    unsigned* __restrict__ tableT,   // [nbucket+1][nsb]
                    unsigned* __restrict__ bdata) {
    __shared__ __align__(16) unsigned ordered[S_PPB];   // 32KB
    __shared__ unsigned hist[NB_MAX];
    __shared__ unsigned sA[NB_MAX], sB[NB_MAX];

    int tid = threadIdx.x;
    int blk = blockIdx.x;

    // fused atom pack: this block's slice
    {
        float par[21];
        compute_par(box, cutoff_p, do_shift_p, par);
        int per = (natoms + nsb - 1) / nsb;
        int a0 = blk * per;
        int a1 = min(natoms, a0 + per);
        for (int i = a0 + tid; i < a1; i += S_TPB) {
            float x = coords[3*i], y = coords[3*i+1], z = coords[3*i+2];
            float sx = x*par[0] + y*par[3] + z*par[6];
            float sy = x*par[1] + y*par[4] + z*par[7];
            float sz = x*par[2] + y*par[5] + z*par[8];
            unsigned qx = (unsigned)__float2int_rn(sx * 65536.0f) & 0xFFFFu;
            unsigned qy = (unsigned)__float2int_rn(sy * 65536.0f) & 0xFFFFu;
            unsigned qz = (unsigned)__float2int_rn(sz * 65536.0f) & 0xFFFFu;
            unsigned qc = (unsigned)__half_as_ushort(__float2half(charges[i]));
            qatoms[i] = make_uint2(qx | (qy << 16), qz | (qc << 16));
        }
    }

    for (int t = tid; t < NB_MAX; t += S_TPB) hist[t] = 0u;
    __syncthreads();

    int base4 = blk * S_I4;
    unsigned k[S_PPT];
    unsigned bs[S_PPT];   // bucket (8b) | seq<<8 ; 0xFFFFFFFF = invalid
#pragma unroll
    for (int u = 0; u < S_UI; ++u) {
        int i4 = base4 + u * S_TPB + tid;
        bool v = (i4 < npair2);
        int4 pp = v ? pairs4[i4] : make_int4(0, 0, 0, 0);
        int u2 = 2 * u;
        if (v) {
            int b0 = (pp.x >> CHUNK_SHIFT) * nchunk + (pp.y >> CHUNK_SHIFT);
            int b1 = (pp.z >> CHUNK_SHIFT) * nchunk + (pp.w >> CHUNK_SHIFT);
            k[u2]     = ((unsigned)(pp.x & (CHUNK-1)) << 16) | (unsigned)(pp.y & (CHUNK-1));
            k[u2 + 1] = ((unsigned)(pp.z & (CHUNK-1)) << 16) | (unsigned)(pp.w & (CHUNK-1));
            unsigned s0 = atomicAdd(&hist[b0], 1u);   // seq = pre-count
            bs[u2] = (unsigned)b0 | (s0 << 8);
            unsigned s1 = atomicAdd(&hist[b1], 1u);
            bs[u2 + 1] = (unsigned)b1 | (s1 << 8);
        } else {
            bs[u2] = 0xFFFFFFFFu; bs[u2 + 1] = 0xFFFFFFFFu;
        }
    }
    __syncthreads();

    // exclusive scan over NB_MAX (Hillis-Steele, ping-pong)
    unsigned *pa = sA, *pb = sB;
    if (tid < NB_MAX) pa[tid] = hist[tid];
    __syncthreads();
    for (int d = 1; d < NB_MAX; d <<= 1) {
        if (tid < NB_MAX) {
            unsigned v = pa[tid];
            if (tid >= d) v += pa[tid - d];
            pb[tid] = v;
        }
        __syncthreads();
        unsigned* t = pa; pa = pb; pb = t;
    }
    // pa = inclusive scan; write TRANSPOSED table column; stash excl in hist
    if (tid <= nbucket) {
        unsigned excl = (tid == 0) ? 0u : pa[tid - 1];
        tableT[(size_t)tid * nsb + blk] = excl;
        if (tid < nbucket) hist[tid] = excl;
    }
    __syncthreads();

    // LDS scatter: slot = excl[bucket] + seq  (no second atomic pass)
#pragma unroll
    for (int u = 0; u < S_PPT; ++u) {
        if (bs[u] != 0xFFFFFFFFu) {
            unsigned b = bs[u] & 0xFFu;
            unsigned slot = hist[b] + (bs[u] >> 8);
            ordered[slot] = k[u];
        }
    }
    __syncthreads();

    // coalesced burst writeout
    unsigned total = pa[nbucket - 1];
    unsigned* dst = bdata + (size_t)blk * S_PPB;
    unsigned n4 = total >> 2;
    const uint4* o4 = (const uint4*)ordered;
    for (unsigned i = tid; i < n4; i += S_TPB)
        ((uint4*)dst)[i] = o4[i];
    for (unsigned i = (n4 << 2) + tid; i < total; i += S_TPB)
        dst[i] = ordered[i];
}

// ---------------- per-bucket compute ----------------

template<bool DIAG>
__device__ __forceinline__ float pair_ener(const uint2* tA, const uint2* tB,
                                           unsigned key, const float* P,
                                           bool valid) {
    uint2 ri = tA[key >> 16];
    uint2 rj = tB[key & 0xFFFFu];
    float dx = (float)(short)(ri.x - rj.x);
    float dy = (float)(short)((ri.x >> 16) - (rj.x >> 16));
    float dz = (float)(short)(ri.y - rj.y);
    float px, py, pz;
    if (DIAG) {
        px = dx * P[11]; py = dy * P[15]; pz = dz * P[19];
    } else {
        px = dx*P[11] + dy*P[14] + dz*P[17];
        py = dx*P[12] + dy*P[15] + dz*P[18];
        pz = dx*P[13] + dy*P[16] + dz*P[19];
    }
    float r2 = px*px + py*py + pz*pz;
    float rinv = rsqrtf(r2);
    float qi = __half2float(__ushort_as_half((unsigned short)(ri.y >> 16)));
    float qj = __half2float(__ushort_as_half((unsigned short)(rj.y >> 16)));
    float e = qi * qj * (rinv - P[10]);
    return (valid && r2 <= P[9]) ? e : 0.0f;
}

// software-pipelined walk (R11 verbatim)
template<bool DIAG>
__device__ double walk(const unsigned* __restrict__ bdata,
                       const unsigned* __restrict__ rowB,
                       const unsigned* __restrict__ rowB1,
                       int sA0, int cnt, int lane,
                       const uint2* tA, const uint2* tB, const float* P) {
    double lsum0 = 0.0, lsum1 = 0.0;
    for (int batch = 0; batch < cnt; batch += 64) {
        int bc = min(64, cnt - batch);
        unsigned o0v = 0u, lnv = 0u;
        if (lane < bc) {
            int s = sA0 + batch + lane;
            unsigned a0 = rowB[s];
            o0v = a0;
            lnv = rowB1[s] - a0;
        }
        unsigned cl0, cl1, cl2, cl3;
        size_t   cb0, cb1, cb2, cb3;
        unsigned ck0, ck1, ck2, ck3;
        {
            unsigned o0 = (unsigned)__shfl((int)o0v, 0);
            cl0 = (0 < bc) ? (unsigned)__shfl((int)lnv, 0) : 0u;
            cb0 = (size_t)(sA0 + batch + 0) * S_PPB + o0;
            unsigned o1 = (unsigned)__shfl((int)o0v, 1);
            cl1 = (1 < bc) ? (unsigned)__shfl((int)lnv, 1) : 0u;
            cb1 = (size_t)(sA0 + batch + 1) * S_PPB + o1;
            unsigned o2 = (unsigned)__shfl((int)o0v, 2);
            cl2 = (2 < bc) ? (unsigned)__shfl((int)lnv, 2) : 0u;
            cb2 = (size_t)(sA0 + batch + 2) * S_PPB + o2;
            unsigned o3 = (unsigned)__shfl((int)o0v, 3);
            cl3 = (3 < bc) ? (unsigned)__shfl((int)lnv, 3) : 0u;
            cb3 = (size_t)(sA0 + batch + 3) * S_PPB + o3;
            ck0 = (lane < (int)cl0) ? bdata[cb0 + lane] : 0u;
            ck1 = (lane < (int)cl1) ? bdata[cb1 + lane] : 0u;
            ck2 = (lane < (int)cl2) ? bdata[cb2 + lane] : 0u;
            ck3 = (lane < (int)cl3) ? bdata[cb3 + lane] : 0u;
        }
        for (int kk = 0; kk < bc; kk += 4) {
            unsigned nl0 = 0u, nl1 = 0u, nl2 = 0u, nl3 = 0u;
            size_t   nb0 = 0,  nb1 = 0,  nb2 = 0,  nb3 = 0;
            unsigned nk0 = 0u, nk1 = 0u, nk2 = 0u, nk3 = 0u;
            if (kk + 4 < bc) {
                unsigned o0 = (unsigned)__shfl((int)o0v, kk + 4);
                nl0 = (unsigned)__shfl((int)lnv, kk + 4);
                nb0 = (size_t)(sA0 + batch + kk + 4) * S_PPB + o0;
                unsigned o1 = (unsigned)__shfl((int)o0v, kk + 5);
                nl1 = (kk + 5 < bc) ? (unsigned)__shfl((int)lnv, kk + 5) : 0u;
                nb1 = (size_t)(sA0 + batch + kk + 5) * S_PPB + o1;
                unsigned o2 = (unsigned)__shfl((int)o0v, kk + 6);
                nl2 = (kk + 6 < bc) ? (unsigned)__shfl((int)lnv, kk + 6) : 0u;
                nb2 = (size_t)(sA0 + batch + kk + 6) * S_PPB + o2;
                unsigned o3 = (unsigned)__shfl((int)o0v, kk + 7);
                nl3 = (kk + 7 < bc) ? (unsigned)__shfl((int)lnv, kk + 7) : 0u;
                nb3 = (size_t)(sA0 + batch + kk + 7) * S_PPB + o3;
                nk0 = (lane < (int)nl0) ? bdata[nb0 + lane] : 0u;
                nk1 = (lane < (int)nl1) ? bdata[nb1 + lane] : 0u;
                nk2 = (lane < (int)nl2) ? bdata[nb2 + lane] : 0u;
                nk3 = (lane < (int)nl3) ? bdata[nb3 + lane] : 0u;
            }
            lsum0 += (double)pair_ener<DIAG>(tA, tB, ck0, P, lane < (int)cl0);
            lsum1 += (double)pair_ener<DIAG>(tA, tB, ck1, P, lane < (int)cl1);
            lsum0 += (double)pair_ener<DIAG>(tA, tB, ck2, P, lane < (int)cl2);
            lsum1 += (double)pair_ener<DIAG>(tA, tB, ck3, P, lane < (int)cl3);
            if (cl0 > 64u) for (unsigned e = 64u + lane; e < cl0; e += 64u)
                lsum0 += (double)pair_ener<DIAG>(tA, tB, bdata[cb0 + e], P, true);
            if (cl1 > 64u) for (unsigned e = 64u + lane; e < cl1; e += 64u)
                lsum1 += (double)pair_ener<DIAG>(tA, tB, bdata[cb1 + e], P, true);
            if (cl2 > 64u) for (unsigned e = 64u + lane; e < cl2; e += 64u)
                lsum0 += (double)pair_ener<DIAG>(tA, tB, bdata[cb2 + e], P, true);
            if (cl3 > 64u) for (unsigned e = 64u + lane; e < cl3; e += 64u)
                lsum1 += (double)pair_ener<DIAG>(tA, tB, bdata[cb3 + e], P, true);
            ck0 = nk0; ck1 = nk1; ck2 = nk2; ck3 = nk3;
            cl0 = nl0; cl1 = nl1; cl2 = nl2; cl3 = nl3;
            cb0 = nb0; cb1 = nb1; cb2 = nb2; cb3 = nb3;
        }
    }
    return lsum0 + lsum1;
}

__global__ __launch_bounds__(C_TPB)
void bucket_compute(const unsigned* __restrict__ bdata,
                    const unsigned* __restrict__ tableT, int nsb,
                    const uint2* __restrict__ qatoms, int natoms, int nchunk,
                    const float* __restrict__ box,
                    const float* __restrict__ cutoff_p,
                    const int* __restrict__ do_shift_p,
                    double* __restrict__ parts) {
    __shared__ __align__(16) uint2 tA[CHUNK];
    __shared__ __align__(16) uint2 tB[CHUNK];
    __shared__ double wsum[C_NW];
    __shared__ float sP[21];

    if (threadIdx.x == 0) compute_par(box, cutoff_p, do_shift_p, sP);

    int b    = blockIdx.x / C_SPLIT;
    int part = blockIdx.x - b * C_SPLIT;
    int bx = b / nchunk, by = b - bx * nchunk;
    int gx = bx << CHUNK_SHIFT, gy = by << CHUNK_SHIFT;

    // uint4 tile staging: 2 atoms/load, chunk-level bounds check
    {
        const uint4* qa4 = reinterpret_cast<const uint4*>(qatoms);
        uint4* tA4 = reinterpret_cast<uint4*>(tA);
        uint4* tB4 = reinterpret_cast<uint4*>(tB);
        if (gx + CHUNK <= natoms) {
            int gx2 = gx >> 1;
            for (int t = threadIdx.x; t < CHUNK / 2; t += C_TPB)
                tA4[t] = qa4[gx2 + t];
        } else {
            for (int t = threadIdx.x; t < CHUNK; t += C_TPB) {
                int ga = gx + t;
                tA[t] = (ga < natoms) ? qatoms[ga] : make_uint2(0u, 0u);
            }
        }
        if (gy + CHUNK <= natoms) {
            int gy2 = gy >> 1;
            for (int t = threadIdx.x; t < CHUNK / 2; t += C_TPB)
                tB4[t] = qa4[gy2 + t];
        } else {
            for (int t = threadIdx.x; t < CHUNK; t += C_TPB) {
                int gb = gy + t;
                tB[t] = (gb < natoms) ? qatoms[gb] : make_uint2(0u, 0u);
            }
        }
    }
    __syncthreads();

    float P[21];
#pragma unroll
    for (int k = 0; k < 21; ++k) P[k] = sP[k];

    int s0 = (int)(((long long)part * nsb) / C_SPLIT);
    int s1 = (int)(((long long)(part + 1) * nsb) / C_SPLIT);
    int lane = threadIdx.x & 63;
    int wid  = threadIdx.x >> 6;

    int nseg = s1 - s0;
    int spw  = (nseg + C_NW - 1) / C_NW;
    int sA0  = s0 + wid * spw;
    int cnt  = min(spw, s1 - sA0);
    if (cnt < 0) cnt = 0;

    const unsigned* rowB  = tableT + (size_t)b * nsb;
    const unsigned* rowB1 = tableT + (size_t)(b + 1) * nsb;

    double lsum = (P[20] != 0.0f)
        ? walk<true >(bdata, rowB, rowB1, sA0, cnt, lane, tA, tB, P)
        : walk<false>(bdata, rowB, rowB1, sA0, cnt, lane, tA, tB, P);

#pragma unroll
    for (int off = 32; off > 0; off >>= 1)
        lsum += __shfl_down(lsum, off);

    if (lane == 0) wsum[wid] = lsum;
    __syncthreads();
    if (threadIdx.x == 0) {
        double s = 0.0;
#pragma unroll
        for (int w = 0; w < C_NW; ++w) s += wsum[w];
        parts[blockIdx.x] = s;
    }
}

// finalize (bucket path): sum partials + odd-pair tail + prefac
__global__ void finalize_bucket(const double* __restrict__ parts, int n,
                                const float* __restrict__ prefac_p,
                                const float* __restrict__ box,
                                const float* __restrict__ cutoff_p,
                                const int* __restrict__ do_shift_p,
                                const float* __restrict__ coords,
                                const float* __restrict__ charges,
                                const int* __restrict__ pairs, int npairs,
                                float* __restrict__ out) {
    __shared__ double sh[4];
    double s = 0.0;
    for (int i = threadIdx.x; i < n; i += 256) s += parts[i];
#pragma unroll
    for (int off = 32; off > 0; off >>= 1) s += __shfl_down(s, off);
    int lane = threadIdx.x & 63, wid = threadIdx.x >> 6;
    if (lane == 0) sh[wid] = s;
    __syncthreads();
    if (threadIdx.x == 0) {
        double tot = sh[0] + sh[1] + sh[2] + sh[3];
        if (npairs & 1) {
            float par[21];
            compute_par(box, cutoff_p, do_shift_p, par);
            int ii = pairs[2*(npairs-1)], jj = pairs[2*(npairs-1)+1];
            float dx = coords[3*ii]-coords[3*jj];
            float dy = coords[3*ii+1]-coords[3*jj+1];
            float dz = coords[3*ii+2]-coords[3*jj+2];
            float sx = dx*par[0]+dy*par[3]+dz*par[6];
            float sy = dx*par[1]+dy*par[4]+dz*par[7];
            float sz = dx*par[2]+dy*par[5]+dz*par[8];
            sx -= floorf(sx+0.5f); sy -= floorf(sy+0.5f); sz -= floorf(sz+0.5f);
            float px = (sx*par[11]+sy*par[14]+sz*par[17])*65536.0f;
            float py = (sx*par[12]+sy*par[15]+sz*par[18])*65536.0f;
            float pz = (sx*par[13]+sy*par[16]+sz*par[19])*65536.0f;
            float r2 = px*px+py*py+pz*pz;
            float e = charges[ii]*charges[jj]*(rsqrtf(r2)-par[10]);
            if (r2 <= par[9]) tot += (double)e;
        }
        out[0] = (float)(tot * (double)(*prefac_p));
    }
}

// ---------------- fallback (direct gather, f32) ----------------

__global__ void setup_kernel(const float* __restrict__ box,
                             const float* __restrict__ cutoff_p,
                             const int* __restrict__ do_shift_p,
                             double* __restrict__ acc,
                             float* __restrict__ par) {
    if (threadIdx.x == 0 && blockIdx.x == 0) {
        *acc = 0.0;
        compute_par(box, cutoff_p, do_shift_p, par);
    }
}

__device__ __forceinline__ float pair_e_f(float4 ai, float4 aj, const float* P) {
    float dx = ai.x - aj.x, dy = ai.y - aj.y, dz = ai.z - aj.z;
    float sx = dx*P[0] + dy*P[3] + dz*P[6];
    float sy = dx*P[1] + dy*P[4] + dz*P[7];
    float sz = dx*P[2] + dy*P[5] + dz*P[8];
    sx -= floorf(sx + 0.5f);
    sy -= floorf(sy + 0.5f);
    sz -= floorf(sz + 0.5f);
    float px = (sx*P[11] + sy*P[14] + sz*P[17]) * 65536.0f;
    float py = (sx*P[12] + sy*P[15] + sz*P[18]) * 65536.0f;
    float pz = (sx*P[13] + sy*P[16] + sz*P[19]) * 65536.0f;
    float r2 = px*px + py*py + pz*pz;
    float rinv = rsqrtf(r2);
    float e = ai.w * aj.w * (rinv - P[10]);
    return (r2 <= P[9]) ? e : 0.0f;
}

__global__ __launch_bounds__(TPB)
void coulomb_direct(const int2* __restrict__ pairs, int npairs,
                    const float* __restrict__ coords,
                    const float* __restrict__ charges,
                    const float* __restrict__ par,
                    double* __restrict__ acc) {
    float P[21];
#pragma unroll
    for (int k = 0; k < 21; ++k) P[k] = par[k];
    double lsum = 0.0;
    int tid = blockIdx.x * blockDim.x + threadIdx.x;
    int stride = gridDim.x * blockDim.x;
    for (int p = tid; p < npairs; p += stride) {
        int2 pr = pairs[p];
        float4 a = make_float4(coords[3*pr.x], coords[3*pr.x+1], coords[3*pr.x+2], charges[pr.x]);
        float4 c = make_float4(coords[3*pr.y], coords[3*pr.y+1], coords[3*pr.y+2], charges[pr.y]);
        lsum += (double)pair_e_f(a, c, P);
    }
#pragma unroll
    for (int off = 32; off > 0; off >>= 1)
        lsum += __shfl_down(lsum, off);
    __shared__ double wsum[TPB / 64];
    int lane = threadIdx.x & 63;
    int wid  = threadIdx.x >> 6;
    if (lane == 0) wsum[wid] = lsum;
    __syncthreads();
    if (threadIdx.x == 0) {
        double s = 0.0;
#pragma unroll
        for (int w = 0; w < TPB / 64; ++w) s += wsum[w];
        atomicAdd(acc, s);
    }
}

__global__ void finalize_kernel(const double* __restrict__ acc,
                                const float* __restrict__ prefac_p,
                                float* __restrict__ out) {
    if (threadIdx.x == 0 && blockIdx.x == 0)
        out[0] = (float)(*acc * (double)(*prefac_p));
}

extern "C" void kernel_launch(void* const* d_in, const int* in_sizes, int n_in,
                              void* d_out, int out_size, void* d_ws, size_t ws_size,
                              hipStream_t stream) {
    const float* coords   = (const float*)d_in[0];
    const int*   pairs    = (const int*)d_in[1];
    const float* box      = (const float*)d_in[2];
    const float* charges  = (const float*)d_in[3];
    const float* prefac   = (const float*)d_in[4];
    const float* cutoff   = (const float*)d_in[5];
    const int*   do_shift = (const int*)d_in[6];
    float* out = (float*)d_out;

    int natoms = in_sizes[0] / 3;
    int npairs = in_sizes[1] / 2;
    int npair2 = npairs / 2;              // int4 count (even region)
    int npairs_even = npair2 * 2;

    int nchunk  = (natoms + CHUNK - 1) >> CHUNK_SHIFT;
    int nbucket = nchunk * nchunk;
    int nsb     = (npairs_even + S_PPB - 1) / S_PPB;

    size_t off_table  = WS_TABLE;
    size_t table_b    = (size_t)(nbucket + 1) * nsb * sizeof(unsigned);
    size_t off_qatoms = (off_table + table_b + 255) & ~(size_t)255;
    size_t off_bdata  = (off_qatoms + (size_t)natoms * sizeof(uint2) + 255) & ~(size_t)255;
    size_t need       = off_bdata + (size_t)nsb * S_PPB * sizeof(unsigned);

    int cblocks = nbucket * C_SPLIT;
    bool use_buckets = (nchunk <= NCHUNK_MAX) && (nbucket <= NB_MAX - 2) &&
                       (nsb >= 1) && (ws_size >= need) && (cblocks <= 4096);

    if (use_buckets) {
        double*   parts  = (double*)((char*)d_ws + WS_PARTS);
        unsigned* tableT = (unsigned*)((char*)d_ws + off_table);
        uint2*    qatoms = (uint2*)((char*)d_ws + off_qatoms);
        unsigned* bdata  = (unsigned*)((char*)d_ws + off_bdata);

        scatter_kernel<<<nsb, S_TPB, 0, stream>>>(
            (const int4*)pairs, npair2, nchunk, nbucket, nsb,
            coords, charges, box, cutoff, do_shift, qatoms, natoms,
            tableT, bdata);

        bucket_compute<<<cblocks, C_TPB, 0, stream>>>(
            bdata, tableT, nsb, qatoms, natoms, nchunk,
            box, cutoff, do_shift, parts);

        finalize_bucket<<<1, 256, 0, stream>>>(
            parts, cblocks, prefac, box, cutoff, do_shift,
            coords, charges, pairs, npairs, out);
    } else {
        double* acc = (double*)((char*)d_ws + WS_ACC);
        float*  par = (float*)((char*)d_ws + WS_PAR);
        setup_kernel<<<1, 64, 0, stream>>>(box, cutoff, do_shift, acc, par);
        int blocks = (npairs + TPB - 1) / TPB;
        if (blocks > 2048) blocks = 2048;
        coulomb_direct<<<blocks, TPB, 0, stream>>>(
            (const int2*)pairs, npairs, coords, charges, par, acc);
        finalize_kernel<<<1, 64, 0, stream>>>(acc, prefac, out);
    }
}